// Round 14
// baseline (293.019 us; speedup 1.0000x reference)
//
#include <hip/hip_runtime.h>
#include <hip/hip_bf16.h>
#include <math.h>

#define BB 4
#define VV 1024
#define HH 128
#define H2 64
#define EE 523776               // V*(V-1)/2
#define BE (BB * EE)            // 2095104
#define TPB64 (EE / 64)         // 8184 64-edge tiles per batch (exact)
#define NT64 (BE / 64)          // 32736
#define NTHR 256
#define NBLK 1024
#define NWAVE (NBLK * 4)        // 4096

typedef __attribute__((ext_vector_type(8))) short bf16x8;
typedef __attribute__((ext_vector_type(4))) float f32x4;
typedef __attribute__((ext_vector_type(4))) unsigned u32x4;

__device__ __forceinline__ short f2bf(float f) {
    __hip_bfloat16 h = __float2bfloat16(f);
    return *reinterpret_cast<short*>(&h);
}

// ONE v_perm_b32: pack two f32 into bf16x2 by truncation (lo -> low half).
__device__ __forceinline__ unsigned pkbf(float lo, float hi) {
    return __builtin_amdgcn_perm(__float_as_uint(hi), __float_as_uint(lo),
                                 0x07060302u);
}

__device__ __forceinline__ bf16x8 relu_pack(f32x4 a, f32x4 b) {
    u32x4 r;
    r[0] = pkbf(fmaxf(a[0], 0.f), fmaxf(a[1], 0.f));
    r[1] = pkbf(fmaxf(a[2], 0.f), fmaxf(a[3], 0.f));
    r[2] = pkbf(fmaxf(b[0], 0.f), fmaxf(b[1], 0.f));
    r[3] = pkbf(fmaxf(b[2], 0.f), fmaxf(b[3], 0.f));
    return __builtin_bit_cast(bf16x8, r);
}

// ---------------------------------------------------------------------------
// Round 14 (= R13 resubmitted after GPU-acquisition timeout): R12's 64-edge
// amortization, restructured so peak register liveness stays ~115 (R12
// spilled at ~170 under the bounds cap):
//   phase 1: 32 L1 MFMAs -> Bh[4][4] bf16 B-frag cache (64 regs, ONLY big set)
//   phase 2: mt-OUTER RUNTIME loop — per mt: 4 accumulators, W2/b2/W3 frags
//            from LDS, L3 folded in as a VALU dot (no Bh3/A3/w3c state).
// All weights in per-lane LDS frag tables (conflict-free ds_read_b128);
// bounds(256,4) targets 4 waves/SIMD (the occupancy every round since R3 has
// been missing). Per-CU budget: LDS 18us, MFMA 25us, VALU 14us -> overlapped
// floor ~25us. Fragment layouts verbatim from R12 (verified passing).
// ---------------------------------------------------------------------------
__global__ __launch_bounds__(NTHR, 4) void edge_mlp_v13(
    const float* __restrict__ vertices,  // [4,1024,3]
    const float* __restrict__ W1,        // [6,128]
    const float* __restrict__ b1,        // [128]
    const float* __restrict__ W2,        // [128,64]
    const float* __restrict__ b2,        // [64]
    const float* __restrict__ W3,        // [64]
    const float* __restrict__ b3,        // [1]
    float* __restrict__ out)             // [BE probs][2*EE indices-as-float]
{
    // bf16 frag ids: 0..7 = A1[p][q1] (id=2p+q1), 8..23 = A2[mt][p] (8+4mt+p)
    __shared__ __align__(16) bf16x8 wA[24 * 64];     // 24 KB
    // f32x4 ids: 0..3 = b2 C-init[mt], 4..7 = w3[mt]
    __shared__ __align__(16) f32x4  wC[8 * 64];      // 8 KB

    const int lane = threadIdx.x & 63;
    const int col  = lane & 15;          // edge slot within a 16-edge subtile
    const int u    = lane >> 4;
    const int wid  = threadIdx.x >> 6;

    const f32x4 zero4 = {0.f, 0.f, 0.f, 0.f};

    // ---- stage 32 frag tables (over 4 waves) ----
    for (int f = wid; f < 32; f += 4) {
        if (f < 8) {
            // A1: row m -> h = 32p + 8*(m>>2) + 4q1 + (m&3); elem r -> k=8u+r
            const int p = f >> 1, q1 = f & 1;
            const int h = 32 * p + 8 * (col >> 2) + 4 * q1 + (col & 3);
            bf16x8 a;
#pragma unroll
            for (int r = 0; r < 8; ++r) {
                const int k = 8 * u + r;
                float w = 0.0f;
                if (k < 6)       w = W1[k * HH + h];
                else if (k == 6) w = b1[h];
                a[r] = f2bf(w);
            }
            wA[f * 64 + lane] = a;
        } else if (f < 24) {
            // A2: row m -> n2 = 32*(mt>>1) + 8*(m>>2) + 4*(mt&1) + (m&3);
            //     elem r -> k = h = 32p + 8u + r
            const int mt = (f - 8) >> 2, p = (f - 8) & 3;
            const int n2 = 32 * (mt >> 1) + 8 * (col >> 2) + 4 * (mt & 1) + (col & 3);
            bf16x8 a;
#pragma unroll
            for (int r = 0; r < 8; ++r)
                a[r] = f2bf(W2[(32 * p + 8 * u + r) * H2 + n2]);
            wA[f * 64 + lane] = a;
        } else if (f < 28) {
            // b2 C-init[mt]: q-component = b2[n2(mt, row=4u+q)]
            const int mt = f - 24;
            f32x4 c;
#pragma unroll
            for (int q = 0; q < 4; ++q)
                c[q] = b2[32 * (mt >> 1) + 8 * u + 4 * (mt & 1) + q];
            wC[mt * 64 + lane] = c;
        } else {
            // w3[mt]: same index map as C-init
            const int mt = f - 28;
            f32x4 c;
#pragma unroll
            for (int q = 0; q < 4; ++q)
                c[q] = W3[32 * (mt >> 1) + 8 * u + 4 * (mt & 1) + q];
            wC[(4 + mt) * 64 + lane] = c;
        }
    }
    const float b3v = b3[0];
    __syncthreads();

    const int gw = blockIdx.x * 4 + wid;

    for (int tt = gw; tt < NT64; tt += NWAVE) {
        const int b  = tt / TPB64;
        const int e0 = (tt - b * TPB64) * 64;

        // ---- decode + feature frags for 4 subtiles (ij packed: 1 reg each) --
        bf16x8 bfv[4];
        int ij[4];
#pragma unroll
        for (int s = 0; s < 4; ++s) {
            const int e  = e0 + s * 16 + col;
            const int rr = EE - 1 - e;
            const float sq = sqrtf((float)(8 * rr + 1));   // exact: < 2^23
            int m = (int)(0.5f * (sq - 1.0f));
            if ((m + 1) * (m + 2) / 2 <= rr) ++m;
            if (m * (m + 1) / 2 > rr) --m;
            const int pp = rr - m * (m + 1) / 2;
            const int iv = VV - 2 - m;
            const int jv = VV - 1 - pp;
            ij[s] = (iv << 16) | jv;
            const float* pvi = vertices + (b * VV + iv) * 3;
            const float* pvj = vertices + (b * VV + jv) * 3;
            u32x4 fb;
            fb[0] = pkbf(pvi[0], pvi[1]);
            fb[1] = pkbf(pvi[2], pvj[0]);
            fb[2] = pkbf(pvj[1], pvj[2]);
            fb[3] = 0x00003F80u;              // bf16(1.0) in k=6 carries b1
            bfv[s] = __builtin_bit_cast(bf16x8, fb);
        }

        // ---- phase 1: L1 -> Bh cache (bfv dies here) ----
        bf16x8 Bh[4][4];                      // [s][p], 64 regs
#pragma unroll
        for (int p = 0; p < 4; ++p) {
            const bf16x8 a1a = wA[(2 * p + 0) * 64 + lane];
            const bf16x8 a1b = wA[(2 * p + 1) * 64 + lane];
#pragma unroll
            for (int s = 0; s < 4; ++s) {
                const f32x4 dA = __builtin_amdgcn_mfma_f32_16x16x32_bf16(a1a, bfv[s], zero4, 0, 0, 0);
                const f32x4 dB = __builtin_amdgcn_mfma_f32_16x16x32_bf16(a1b, bfv[s], zero4, 0, 0, 0);
                Bh[s][p] = relu_pack(dA, dB);
            }
        }

        // ---- phase 2: mt-outer (runtime loop bounds liveness); L3 folded ----
        float acc0 = 0.f, acc1 = 0.f, acc2 = 0.f, acc3 = 0.f;
        for (int mt = 0; mt < 4; ++mt) {
            const f32x4 cini = wC[mt * 64 + lane];
            f32x4 d2s[4];
#pragma unroll
            for (int s = 0; s < 4; ++s) d2s[s] = cini;
#pragma unroll
            for (int p = 0; p < 4; ++p) {
                const bf16x8 w2 = wA[(8 + 4 * mt + p) * 64 + lane];
#pragma unroll
                for (int s = 0; s < 4; ++s)
                    d2s[s] = __builtin_amdgcn_mfma_f32_16x16x32_bf16(w2, Bh[s][p], d2s[s], 0, 0, 0);
            }
            const f32x4 w3v = wC[(4 + mt) * 64 + lane];
            acc0 += fmaxf(d2s[0][0],0.f)*w3v[0] + fmaxf(d2s[0][1],0.f)*w3v[1]
                  + fmaxf(d2s[0][2],0.f)*w3v[2] + fmaxf(d2s[0][3],0.f)*w3v[3];
            acc1 += fmaxf(d2s[1][0],0.f)*w3v[0] + fmaxf(d2s[1][1],0.f)*w3v[1]
                  + fmaxf(d2s[1][2],0.f)*w3v[2] + fmaxf(d2s[1][3],0.f)*w3v[3];
            acc2 += fmaxf(d2s[2][0],0.f)*w3v[0] + fmaxf(d2s[2][1],0.f)*w3v[1]
                  + fmaxf(d2s[2][2],0.f)*w3v[2] + fmaxf(d2s[2][3],0.f)*w3v[3];
            acc3 += fmaxf(d2s[3][0],0.f)*w3v[0] + fmaxf(d2s[3][1],0.f)*w3v[1]
                  + fmaxf(d2s[3][2],0.f)*w3v[2] + fmaxf(d2s[3][3],0.f)*w3v[3];
        }

        // ---- epilogue: reduce across u, sigmoid, store ----
        float accv[4] = {acc0, acc1, acc2, acc3};
#pragma unroll
        for (int s = 0; s < 4; ++s) {
            float acc = accv[s];
            acc += __shfl_xor(acc, 16);
            acc += __shfl_xor(acc, 32);
            if (u == 0) {
                const float prob = __builtin_amdgcn_rcpf(1.0f + __expf(-(acc + b3v)));
                out[tt * 64 + s * 16 + col] = prob;   // == b*EE + e0 + s*16+col
                if (b == 0) {
                    const int e = e0 + s * 16 + col;
                    *(float2*)(&out[BE + 2 * e]) =
                        make_float2((float)(ij[s] >> 16), (float)(ij[s] & 0xffff));
                }
            }
        }
    }
}

extern "C" void kernel_launch(void* const* d_in, const int* in_sizes, int n_in,
                              void* d_out, int out_size, void* d_ws, size_t ws_size,
                              hipStream_t stream) {
    const float* vertices = (const float*)d_in[0];
    const float* W1 = (const float*)d_in[1];
    const float* b1 = (const float*)d_in[2];
    const float* W2 = (const float*)d_in[3];
    const float* b2 = (const float*)d_in[4];
    const float* W3 = (const float*)d_in[5];
    const float* b3 = (const float*)d_in[6];
    float* out = (float*)d_out;

    edge_mlp_v13<<<NBLK, NTHR, 0, stream>>>(vertices, W1, b1, W2, b2, W3, b3, out);
}

// Round 15
// 225.885 us; speedup vs baseline: 1.2972x; 1.2972x over previous
//
#include <hip/hip_runtime.h>
#include <hip/hip_bf16.h>
#include <math.h>

#define BB 4
#define VV 1024
#define HH 128
#define H2 64
#define EE 523776               // V*(V-1)/2
#define BE (BB * EE)            // 2095104
#define TPB (EE / 16)           // 32736 tiles per batch
#define NTILES (BE / 16)        // 130944
#define NTHR 256
#define NBLK 1024
#define NWAVE (NBLK * 4)        // 4096
#define PQN (BB * VV * HH)      // 524288

typedef __attribute__((ext_vector_type(8))) short bf16x8;
typedef __attribute__((ext_vector_type(4))) float f32x4;
typedef __attribute__((ext_vector_type(4))) unsigned u32x4;

__device__ __forceinline__ short f2bf(float f) {
    __hip_bfloat16 h = __float2bfloat16(f);
    return *reinterpret_cast<short*>(&h);
}

// ONE v_perm_b32: pack two f32 into bf16x2 by truncation (lo -> low half).
__device__ __forceinline__ unsigned pkbf(float lo, float hi) {
    return __builtin_amdgcn_perm(__float_as_uint(hi), __float_as_uint(lo),
                                 0x07060302u);
}

__device__ __forceinline__ bf16x8 relu_pack(f32x4 a, f32x4 b) {
    u32x4 r;
    r[0] = pkbf(fmaxf(a[0], 0.f), fmaxf(a[1], 0.f));
    r[1] = pkbf(fmaxf(a[2], 0.f), fmaxf(a[3], 0.f));
    r[2] = pkbf(fmaxf(b[0], 0.f), fmaxf(b[1], 0.f));
    r[3] = pkbf(fmaxf(b[2], 0.f), fmaxf(b[3], 0.f));
    return __builtin_bit_cast(bf16x8, r);
}

// ---------------------------------------------------------------------------
// Kernel 1 (verified in R10): per-vertex L1 precompute.
//   P[v][h] = W1[0:3,h]·vert,  Q[v][h] = W1[3:6,h]·vert + b1[h]
// => h1(i,j) = relu(P[i] + Q[j]) exactly replaces layer 1 (f32-exact, better
// than the previous bf16-input L1 MFMA path).
// ---------------------------------------------------------------------------
__global__ __launch_bounds__(NTHR) void pq_kernel(
    const float* __restrict__ vertices, const float* __restrict__ W1,
    const float* __restrict__ b1, float* __restrict__ P, float* __restrict__ Q)
{
    const int t = blockIdx.x * NTHR + threadIdx.x;   // 0..PQN-1, exact grid
    const int v = t >> 7;            // global vertex 0..4095
    const int h = t & 127;
    const float x = vertices[v * 3 + 0];
    const float y = vertices[v * 3 + 1];
    const float z = vertices[v * 3 + 2];
    P[t] = fmaf(x, W1[0 * HH + h], fmaf(y, W1[1 * HH + h], z * W1[2 * HH + h]));
    Q[t] = fmaf(x, W1[3 * HH + h], fmaf(y, W1[4 * HH + h],
                fmaf(z, W1[5 * HH + h], b1[h])));
}

// ---------------------------------------------------------------------------
// Round 15: R11's proven skeleton (A2 resident 64 regs, cinit/A3 LDS tables,
// L3-as-MFMA, bounds(256,3) — the one non-spilling config) with layer 1
// REPLACED by P/Q global adds: the L2 B-frag is built directly as
//   Bf[p][r] = bf16(relu(P[i][32p+8u+r] + Q[j][32p+8u+r]))
// (fragment layout == natural P/Q row layout; float4 loads, coalesced in col,
// P broadcast). Deletes per tile: 8 L1 MFMAs + their packs + 8 A1 LDS reads
// + vertex gather — the longest dependency chain and most of the LDS pipe
// time (14 -> 6 reads/tile; R11 measured-modeled 36us/CU of serial LDS).
// ---------------------------------------------------------------------------
__global__ __launch_bounds__(NTHR, 3) void edge_mlp_v15(
    const float* __restrict__ P,      // [4096,128] f32 (ws)
    const float* __restrict__ Q,      // [4096,128] f32 (ws)
    const float* __restrict__ W2,     // [128,64]
    const float* __restrict__ b2,     // [64]
    const float* __restrict__ W3,     // [64]
    const float* __restrict__ b3,     // [1]
    float* __restrict__ out)          // [BE probs][2*EE indices-as-float]
{
    // LDS frag tables: f32x4 ids 0..3 = b2 C-init[mt]; bf16x8 ids 0..1 = A3[t]
    __shared__ __align__(16) f32x4  wC[4 * 64];      // 4 KB
    __shared__ __align__(16) bf16x8 wA3[2 * 64];     // 2 KB

    const int lane = threadIdx.x & 63;
    const int col  = lane & 15;          // edge slot (N dim everywhere)
    const int u    = lane >> 4;
    const int wid  = threadIdx.x >> 6;

    // ---- A2 resident (64 regs; R11-verified layout):
    // A2r[mt*4+p] row m -> n2 = 32*(mt>>1) + 8*(m>>2) + 4*(mt&1) + (m&3),
    // elem r -> k = h = 32p + 8u + r.  Row permutation makes L2's D output
    // land exactly in L3's B-frag slots.
    bf16x8 A2r[16];
#pragma unroll
    for (int mt = 0; mt < 4; ++mt) {
        const int n2 = 32 * (mt >> 1) + 8 * (col >> 2) + 4 * (mt & 1) + (col & 3);
#pragma unroll
        for (int p = 0; p < 4; ++p)
#pragma unroll
            for (int r = 0; r < 8; ++r)
                A2r[mt * 4 + p][r] = f2bf(W2[(32 * p + 8 * u + r) * H2 + n2]);
    }

    // ---- stage the 6 small LDS tables ----
    if (wid == 0) {
#pragma unroll
        for (int mt = 0; mt < 4; ++mt) {
            f32x4 c;
#pragma unroll
            for (int q = 0; q < 4; ++q)
                c[q] = b2[32 * (mt >> 1) + 8 * u + 4 * (mt & 1) + q];
            wC[mt * 64 + lane] = c;
        }
    } else if (wid == 1) {
#pragma unroll
        for (int t = 0; t < 2; ++t) {
            bf16x8 a;
#pragma unroll
            for (int r = 0; r < 8; ++r) a[r] = f2bf(W3[32 * t + 8 * u + r]);
            wA3[t * 64 + lane] = a;
        }
    }
    const float b3v = b3[0];
    __syncthreads();

    const int gw = blockIdx.x * 4 + wid;
    const int off0 = 8 * u;              // this lane's element offset in a row

    for (int tt = gw; tt < NTILES; tt += NWAVE) {
        const int b  = tt / TPB;
        const int e0 = (tt - b * TPB) * 16;
        const int e  = e0 + col;

        // ---- decode e -> (i,j): reverse-triangular, exact f32 ----
        const int rr = EE - 1 - e;
        const float sq = sqrtf((float)(8 * rr + 1));
        int m = (int)(0.5f * (sq - 1.0f));
        if ((m + 1) * (m + 2) / 2 <= rr) ++m;
        if (m * (m + 1) / 2 > rr) --m;
        const int pp = rr - m * (m + 1) / 2;
        const int iv = VV - 2 - m;
        const int jv = VV - 1 - pp;

        const float* Pi = P + (((b << 10) + iv) << 7) + off0;
        const float* Qj = Q + (((b << 10) + jv) << 7) + off0;

        // ---- build L2 B-frags: relu(P+Q) truncation-packed, 4 k-tiles ----
        bf16x8 Bf[4];
#pragma unroll
        for (int p = 0; p < 4; ++p) {
            const float4 pa = *(const float4*)(Pi + 32 * p);
            const float4 pb = *(const float4*)(Pi + 32 * p + 4);
            const float4 qa = *(const float4*)(Qj + 32 * p);
            const float4 qb = *(const float4*)(Qj + 32 * p + 4);
            u32x4 rrp;
            rrp[0] = pkbf(fmaxf(pa.x + qa.x, 0.f), fmaxf(pa.y + qa.y, 0.f));
            rrp[1] = pkbf(fmaxf(pa.z + qa.z, 0.f), fmaxf(pa.w + qa.w, 0.f));
            rrp[2] = pkbf(fmaxf(pb.x + qb.x, 0.f), fmaxf(pb.y + qb.y, 0.f));
            rrp[3] = pkbf(fmaxf(pb.z + qb.z, 0.f), fmaxf(pb.w + qb.w, 0.f));
            Bf[p] = __builtin_bit_cast(bf16x8, rrp);
        }

        // ---- layer 2: 16 MFMA, C-init = b2 (LDS) ----
        f32x4 d2_0 = wC[0 * 64 + lane];
        f32x4 d2_1 = wC[1 * 64 + lane];
        f32x4 d2_2 = wC[2 * 64 + lane];
        f32x4 d2_3 = wC[3 * 64 + lane];
#pragma unroll
        for (int p = 0; p < 4; ++p) {
            d2_0 = __builtin_amdgcn_mfma_f32_16x16x32_bf16(A2r[0 * 4 + p], Bf[p], d2_0, 0, 0, 0);
            d2_1 = __builtin_amdgcn_mfma_f32_16x16x32_bf16(A2r[1 * 4 + p], Bf[p], d2_1, 0, 0, 0);
            d2_2 = __builtin_amdgcn_mfma_f32_16x16x32_bf16(A2r[2 * 4 + p], Bf[p], d2_2, 0, 0, 0);
            d2_3 = __builtin_amdgcn_mfma_f32_16x16x32_bf16(A2r[3 * 4 + p], Bf[p], d2_3, 0, 0, 0);
        }

        // ---- layer 3 as MFMA (L2 D-layout IS the L3 B-frag; R11-verified) --
        const bf16x8 Bh3_0 = relu_pack(d2_0, d2_1);
        const bf16x8 Bh3_1 = relu_pack(d2_2, d2_3);
        f32x4 d3 = {b3v, b3v, b3v, b3v};
        d3 = __builtin_amdgcn_mfma_f32_16x16x32_bf16(wA3[0 * 64 + lane], Bh3_0, d3, 0, 0, 0);
        d3 = __builtin_amdgcn_mfma_f32_16x16x32_bf16(wA3[1 * 64 + lane], Bh3_1, d3, 0, 0, 0);

        if (u == 0) {
            const float prob = __builtin_amdgcn_rcpf(1.0f + __expf(-d3[0]));
            out[tt * 16 + col] = prob;        // tt*16 == b*EE + e0
            if (b == 0)
                *(float2*)(&out[BE + 2 * e]) = make_float2((float)iv, (float)jv);
        }
    }
}

extern "C" void kernel_launch(void* const* d_in, const int* in_sizes, int n_in,
                              void* d_out, int out_size, void* d_ws, size_t ws_size,
                              hipStream_t stream) {
    const float* vertices = (const float*)d_in[0];
    const float* W1 = (const float*)d_in[1];
    const float* b1 = (const float*)d_in[2];
    const float* W2 = (const float*)d_in[3];
    const float* b2 = (const float*)d_in[4];
    const float* W3 = (const float*)d_in[5];
    const float* b3 = (const float*)d_in[6];
    float* out = (float*)d_out;

    float* P = (float*)d_ws;            // 2 MB
    float* Q = P + PQN;                 // 2 MB (ws_size >= 4 MB; ok in R10)

    pq_kernel<<<PQN / NTHR, NTHR, 0, stream>>>(vertices, W1, b1, P, Q);
    edge_mlp_v15<<<NBLK, NTHR, 0, stream>>>(P, Q, W2, b2, W3, b3, out);
}